// Round 1
// baseline (586.390 us; speedup 1.0000x reference)
//
#include <hip/hip_runtime.h>
#include <hip/hip_bf16.h>

typedef __bf16 bf16x8 __attribute__((ext_vector_type(8)));
typedef __bf16 bf16x4 __attribute__((ext_vector_type(4)));
typedef float  f32x4  __attribute__((ext_vector_type(4)));

#define SLEN  2048
#define DHEAD 128
#define QBLK  64
#define KVBLK 32
#define NWAVE 4

__device__ __forceinline__ bf16x8 cvt8(float4 a, float4 b) {
    bf16x8 r;
    r[0]=(__bf16)a.x; r[1]=(__bf16)a.y; r[2]=(__bf16)a.z; r[3]=(__bf16)a.w;
    r[4]=(__bf16)b.x; r[5]=(__bf16)b.y; r[6]=(__bf16)b.z; r[7]=(__bf16)b.w;
    return r;
}

__global__ __launch_bounds__(256) void attn_fwd(
    const float* __restrict__ Q, const float* __restrict__ K,
    const float* __restrict__ V, float* __restrict__ O)
{
    const int qt   = blockIdx.x;   // 0..31  (q tile of 64)
    const int bh   = blockIdx.y;   // 0..31  (batch*head)
    const int tid  = threadIdx.x;
    const int w    = tid >> 6;     // wave 0..3
    const int lane = tid & 63;
    const int r    = lane & 15;    // 16-group index
    const int g    = lane >> 4;    // quarter-wave 0..3

    const size_t head_off = (size_t)bh * SLEN * DHEAD;
    const float* Qh = Q + head_off;
    const float* Kh = K + head_off;
    const float* Vh = V + head_off;
    float*       Oh = O + head_off;

    const int q0w = qt * QBLK + w * 16;   // this wave's first q row

    // per-wave P staging: 16 q rows x 32 kv, stride 36 bf16 (72B) -> 18r mod 32
    // bank spread: all 16 rows land on distinct bank pairs for b64 reads.
    __shared__ __bf16 P_lds[NWAVE][16][36];

    const float scale = 0.08838834764831845f; // 1/sqrt(128)

    // ---- Q fragments (A operand): row = q0w + r, k = g*8 + kb*32 + e ----
    bf16x8 qfrag[4];
    {
        const float4* qp = reinterpret_cast<const float4*>(
            Qh + (size_t)(q0w + r) * DHEAD + g * 8);
        #pragma unroll
        for (int kb = 0; kb < 4; ++kb) {
            float4 a = qp[kb*8 + 0];
            float4 b = qp[kb*8 + 1];
            // fold softmax scale into Q in fp32 before bf16 rounding
            a.x*=scale; a.y*=scale; a.z*=scale; a.w*=scale;
            b.x*=scale; b.y*=scale; b.z*=scale; b.w*=scale;
            qfrag[kb] = cvt8(a, b);
        }
    }

    const f32x4 vzero = {0.f, 0.f, 0.f, 0.f};
    f32x4 acc_o[8];
    #pragma unroll
    for (int i = 0; i < 8; ++i) acc_o[i] = vzero;
    float m_run[4], l_run[4];
    #pragma unroll
    for (int e = 0; e < 4; ++e) { m_run[e] = -1e30f; l_run[e] = 0.f; }

    // causal: this wave's rows reach q0w+15 -> last kv tile index:
    const int kvt_max = (q0w + 15) >> 5;   // inclusive

    for (int kvt = 0; kvt <= kvt_max; ++kvt) {
        const int kv0 = kvt * KVBLK;

        // ---- QK^T: two 16(kv)-tiles, K=128 in 4 steps ----
        f32x4 acc_s[2];
        #pragma unroll
        for (int t = 0; t < 2; ++t) {
            const float4* kp = reinterpret_cast<const float4*>(
                Kh + (size_t)(kv0 + t*16 + r) * DHEAD + g * 8);
            acc_s[t] = vzero;
            #pragma unroll
            for (int kb = 0; kb < 4; ++kb) {
                bf16x8 kf = cvt8(kp[kb*8], kp[kb*8 + 1]);
                acc_s[t] = __builtin_amdgcn_mfma_f32_16x16x32_bf16(
                    qfrag[kb], kf, acc_s[t], 0, 0, 0);
            }
        }

        // ---- online softmax; D layout: row q0w+g*4+e, col kv0+t*16+r ----
        float corr[4];
        #pragma unroll
        for (int e = 0; e < 4; ++e) {
            const int qrow = q0w + g*4 + e;
            float s0 = acc_s[0][e];
            float s1 = acc_s[1][e];
            if (kv0      + r > qrow) s0 = -1e30f;
            if (kv0 + 16 + r > qrow) s1 = -1e30f;
            float tm = fmaxf(s0, s1);
            tm = fmaxf(tm, __shfl_xor(tm, 1));
            tm = fmaxf(tm, __shfl_xor(tm, 2));
            tm = fmaxf(tm, __shfl_xor(tm, 4));
            tm = fmaxf(tm, __shfl_xor(tm, 8));
            const float m_new = fmaxf(m_run[e], tm);
            const float p0 = __expf(s0 - m_new);
            const float p1 = __expf(s1 - m_new);
            float rs = p0 + p1;
            rs += __shfl_xor(rs, 1);
            rs += __shfl_xor(rs, 2);
            rs += __shfl_xor(rs, 4);
            rs += __shfl_xor(rs, 8);
            corr[e]  = __expf(m_run[e] - m_new);
            l_run[e] = l_run[e] * corr[e] + rs;
            m_run[e] = m_new;
            P_lds[w][g*4 + e][r]      = (__bf16)p0;
            P_lds[w][g*4 + e][16 + r] = (__bf16)p1;
        }

        // rescale O accumulator
        #pragma unroll
        for (int dt = 0; dt < 8; ++dt)
            #pragma unroll
            for (int e = 0; e < 4; ++e)
                acc_o[dt][e] *= corr[e];

        // wave-local LDS: drain writes before re-reading (no block barrier
        // needed -- each wave owns its P_lds slab; DS ops complete in order)
        asm volatile("s_waitcnt lgkmcnt(0)" ::: "memory");

        // ---- P as A-fragment: row = r, k = g*8 + e ----
        bf16x4 plo = *reinterpret_cast<const bf16x4*>(&P_lds[w][r][g*8]);
        bf16x4 phi = *reinterpret_cast<const bf16x4*>(&P_lds[w][r][g*8 + 4]);
        bf16x8 pa;
        #pragma unroll
        for (int j = 0; j < 4; ++j) { pa[j] = plo[j]; pa[4+j] = phi[j]; }

        // ---- PV: B-fragment = V[kv0+g*8+e][dt*16 + r] (column reads) ----
        const float* vp = Vh + (size_t)(kv0 + g*8) * DHEAD + r;
        #pragma unroll
        for (int dt = 0; dt < 8; ++dt) {
            bf16x8 vf;
            #pragma unroll
            for (int e = 0; e < 8; ++e)
                vf[e] = (__bf16)vp[e*DHEAD + dt*16];
            acc_o[dt] = __builtin_amdgcn_mfma_f32_16x16x32_bf16(
                pa, vf, acc_o[dt], 0, 0, 0);
        }
    }

    // ---- epilogue: O = acc / l ----
    #pragma unroll
    for (int e = 0; e < 4; ++e) {
        const float inv = 1.0f / l_run[e];
        float* orow = Oh + (size_t)(q0w + g*4 + e) * DHEAD + r;
        #pragma unroll
        for (int dt = 0; dt < 8; ++dt)
            orow[dt*16] = acc_o[dt][e] * inv;
    }
}

extern "C" void kernel_launch(void* const* d_in, const int* in_sizes, int n_in,
                              void* d_out, int out_size, void* d_ws, size_t ws_size,
                              hipStream_t stream) {
    const float* Q = (const float*)d_in[0];
    const float* K = (const float*)d_in[1];
    const float* V = (const float*)d_in[2];
    float* O = (float*)d_out;
    dim3 grid(SLEN / QBLK, 32 /* B*H */);
    attn_fwd<<<grid, 256, 0, stream>>>(Q, K, V, O);
}

// Round 2
// 186.147 us; speedup vs baseline: 3.1501x; 3.1501x over previous
//
#include <hip/hip_runtime.h>
#include <hip/hip_bf16.h>

typedef __bf16 bf16x8 __attribute__((ext_vector_type(8)));
typedef __bf16 bf16x4 __attribute__((ext_vector_type(4)));
typedef float  f32x4  __attribute__((ext_vector_type(4)));

#define SLEN  2048
#define DHEAD 128
#define QBLK  64     // q rows per block (4 waves x 16)
#define KVBLK 64     // kv rows staged per iteration
#define NQT   (SLEN / QBLK)

__global__ __launch_bounds__(256) void attn_fwd(
    const float* __restrict__ Q, const float* __restrict__ K,
    const float* __restrict__ V, float* __restrict__ O)
{
    const int bh = blockIdx.x;            // head fastest -> equal-length dispatch wavefronts
    const int qt = (NQT - 1) - blockIdx.y; // LPT: longest blocks dispatched first
    const int tid  = threadIdx.x;
    const int w    = tid >> 6;            // wave 0..3
    const int lane = tid & 63;
    const int r    = lane & 15;
    const int g    = lane >> 4;

    const size_t head_off = (size_t)bh * SLEN * DHEAD;
    const float* Qh = Q + head_off;
    const float* Kh = K + head_off;
    const float* Vh = V + head_off;
    float*       Oh = O + head_off;

    const int q0w = qt * QBLK + w * 16;   // this wave's first q row

    // K tile: [64][128] bf16 row-major, byte ^= ((row&7)<<4)
    __shared__ __bf16 K_sh[KVBLK * DHEAD];
    // V^T tile: [128][64] bf16 row-major (row=d), byte ^= ((d&7)<<4)
    __shared__ __bf16 Vt_sh[DHEAD * KVBLK];
    // P: per-wave [16 qrows][72] (64 + 8 pad)
    __shared__ __bf16 P_sh[4 * 16 * 72];

    char* Kb  = reinterpret_cast<char*>(K_sh);
    char* Vtb = reinterpret_cast<char*>(Vt_sh);
    char* Pb  = reinterpret_cast<char*>(P_sh);

    const float scale = 0.08838834764831845f; // 1/sqrt(128)

    // ---- Q fragments (A operand): row = q0w + r, k = kb*32 + g*8 + e ----
    bf16x8 qfrag[4];
    {
        const float4* qp = reinterpret_cast<const float4*>(
            Qh + (size_t)(q0w + r) * DHEAD + g * 8);
        #pragma unroll
        for (int kb = 0; kb < 4; ++kb) {
            float4 a = qp[kb*8 + 0];
            float4 b = qp[kb*8 + 1];
            a.x*=scale; a.y*=scale; a.z*=scale; a.w*=scale;
            b.x*=scale; b.y*=scale; b.z*=scale; b.w*=scale;
            bf16x8 f;
            f[0]=(__bf16)a.x; f[1]=(__bf16)a.y; f[2]=(__bf16)a.z; f[3]=(__bf16)a.w;
            f[4]=(__bf16)b.x; f[5]=(__bf16)b.y; f[6]=(__bf16)b.z; f[7]=(__bf16)b.w;
            qfrag[kb] = f;
        }
    }

    const f32x4 vzero = {0.f, 0.f, 0.f, 0.f};
    f32x4 acc_o[8];
    #pragma unroll
    for (int i = 0; i < 8; ++i) acc_o[i] = vzero;
    float m_run[4], l_run[4];
    #pragma unroll
    for (int e = 0; e < 4; ++e) { m_run[e] = -1e30f; l_run[e] = 0.f; }

    for (int kvt = 0; kvt <= qt; ++kvt) {
        const int kv0 = kvt * KVBLK;

        // ================= stage K (coalesced) =================
        // 2048 float4 elems; 8 per thread. idx -> row=idx>>5, c4=idx&31
        #pragma unroll
        for (int it = 0; it < 8; ++it) {
            const int idx = it * 256 + tid;
            const int row = idx >> 5;
            const int c4  = idx & 31;
            float4 kvv = *reinterpret_cast<const float4*>(
                Kh + (size_t)(kv0 + row) * DHEAD + c4 * 4);
            bf16x4 kb4;
            kb4[0]=(__bf16)kvv.x; kb4[1]=(__bf16)kvv.y;
            kb4[2]=(__bf16)kvv.z; kb4[3]=(__bf16)kvv.w;
            const int byte = row * 256 + ((c4 * 8) ^ ((row & 7) << 4));
            *reinterpret_cast<bf16x4*>(Kb + byte) = kb4;
        }

        // ================= stage V transposed =================
        // lane covers kv (row), wave covers 32-col slab -> conflict-free b16 writes
        {
            const int kvr   = lane;           // 0..63
            const int cbase = w * 32;         // wave's column slab
            const float* vrow = Vh + (size_t)(kv0 + kvr) * DHEAD;
            #pragma unroll
            for (int it = 0; it < 8; ++it) {
                const int c = cbase + it * 4;
                float4 v4 = *reinterpret_cast<const float4*>(vrow + c);
                #pragma unroll
                for (int j = 0; j < 4; ++j) {
                    const int d = c + j;
                    const int byte = d * 128 + ((kvr * 2) ^ ((d & 7) << 4));
                    *reinterpret_cast<__bf16*>(Vtb + byte) = (__bf16)((&v4.x)[j]);
                }
            }
        }

        __syncthreads();

        // ================= QK^T: 4 kv-subtiles of 16 =================
        f32x4 acc_s[4];
        #pragma unroll
        for (int t = 0; t < 4; ++t) {
            acc_s[t] = vzero;
            #pragma unroll
            for (int kb = 0; kb < 4; ++kb) {
                const int row  = t * 16 + r;
                const int byte = row * 256 + ((kb*64 + g*16) ^ ((r & 7) << 4));
                bf16x8 kf = *reinterpret_cast<const bf16x8*>(Kb + byte);
                acc_s[t] = __builtin_amdgcn_mfma_f32_16x16x32_bf16(
                    qfrag[kb], kf, acc_s[t], 0, 0, 0);
            }
        }

        // ================= online softmax =================
        const bool diag = (kvt == qt);
        float corr[4];
        #pragma unroll
        for (int e = 0; e < 4; ++e) {
            const int qrow = q0w + g*4 + e;
            float s[4];
            #pragma unroll
            for (int t = 0; t < 4; ++t) {
                s[t] = acc_s[t][e];
                if (diag && (kv0 + t*16 + r > qrow)) s[t] = -1e30f;
            }
            float tm = fmaxf(fmaxf(s[0], s[1]), fmaxf(s[2], s[3]));
            tm = fmaxf(tm, __shfl_xor(tm, 1));
            tm = fmaxf(tm, __shfl_xor(tm, 2));
            tm = fmaxf(tm, __shfl_xor(tm, 4));
            tm = fmaxf(tm, __shfl_xor(tm, 8));
            const float m_new = fmaxf(m_run[e], tm);
            float p[4], rs = 0.f;
            #pragma unroll
            for (int t = 0; t < 4; ++t) { p[t] = __expf(s[t] - m_new); rs += p[t]; }
            rs += __shfl_xor(rs, 1);
            rs += __shfl_xor(rs, 2);
            rs += __shfl_xor(rs, 4);
            rs += __shfl_xor(rs, 8);
            corr[e]  = __expf(m_run[e] - m_new);
            l_run[e] = l_run[e] * corr[e] + rs;
            m_run[e] = m_new;
            #pragma unroll
            for (int t = 0; t < 4; ++t)
                P_sh[(w*16 + g*4 + e) * 72 + t*16 + r] = (__bf16)p[t];
        }

        // rescale O accumulator
        #pragma unroll
        for (int dt = 0; dt < 8; ++dt)
            #pragma unroll
            for (int e = 0; e < 4; ++e)
                acc_o[dt][e] *= corr[e];

        // wave-local P round-trip: drain DS writes (compiler memory barrier;
        // DS pipe is in-order per wave)
        asm volatile("s_waitcnt lgkmcnt(0)" ::: "memory");

        // ================= PV =================
        #pragma unroll
        for (int ks = 0; ks < 2; ++ks) {
            const int pbyte = (w*16 + r) * 144 + ks*64 + g*16;
            bf16x8 pa = *reinterpret_cast<const bf16x8*>(Pb + pbyte);
            #pragma unroll
            for (int dt = 0; dt < 8; ++dt) {
                const int row  = dt*16 + r;
                const int byte = row * 128 + ((ks*64 + g*16) ^ ((r & 7) << 4));
                bf16x8 vf = *reinterpret_cast<const bf16x8*>(Vtb + byte);
                acc_o[dt] = __builtin_amdgcn_mfma_f32_16x16x32_bf16(
                    pa, vf, acc_o[dt], 0, 0, 0);
            }
        }

        __syncthreads();  // protect K_sh/Vt_sh before next stage
    }

    // ---- epilogue: O = acc / l ----
    #pragma unroll
    for (int e = 0; e < 4; ++e) {
        const float inv = 1.0f / l_run[e];
        float* orow = Oh + (size_t)(q0w + g*4 + e) * DHEAD + r;
        #pragma unroll
        for (int dt = 0; dt < 8; ++dt)
            orow[dt*16] = acc_o[dt][e] * inv;
    }
}

extern "C" void kernel_launch(void* const* d_in, const int* in_sizes, int n_in,
                              void* d_out, int out_size, void* d_ws, size_t ws_size,
                              hipStream_t stream) {
    const float* Q = (const float*)d_in[0];
    const float* K = (const float*)d_in[1];
    const float* V = (const float*)d_in[2];
    float* O = (float*)d_out;
    dim3 grid(32 /* B*H */, NQT);
    attn_fwd<<<grid, 256, 0, stream>>>(Q, K, V, O);
}

// Round 3
// 114.797 us; speedup vs baseline: 5.1081x; 1.6215x over previous
//
#include <hip/hip_runtime.h>
#include <hip/hip_bf16.h>

typedef __bf16 bf16x8 __attribute__((ext_vector_type(8)));
typedef __bf16 bf16x4 __attribute__((ext_vector_type(4)));
typedef float  f32x4  __attribute__((ext_vector_type(4)));

#define SLEN  2048
#define DHEAD 128
#define QBLK  64     // q rows per block (4 waves x 16)
#define KVBLK 64     // kv rows staged per iteration
#define NQT   (SLEN / QBLK)

__global__ __launch_bounds__(256, 2) void attn_fwd(
    const float* __restrict__ Q, const float* __restrict__ K,
    const float* __restrict__ V, float* __restrict__ O)
{
    const int bh = blockIdx.x;             // head fastest
    const int qt = (NQT - 1) - blockIdx.y; // LPT: longest first
    const int tid  = threadIdx.x;
    const int w    = tid >> 6;
    const int lane = tid & 63;
    const int r    = lane & 15;
    const int g    = lane >> 4;

    const size_t head_off = (size_t)bh * SLEN * DHEAD;
    const float* Qh = Q + head_off;
    const float* Kh = K + head_off;
    const float* Vh = V + head_off;
    float*       Oh = O + head_off;

    const int q0w = qt * QBLK + w * 16;

    // double-buffered tiles; byte ^= ((row&7)<<4) swizzle on both sides
    __shared__ __bf16 K_sh [2][KVBLK * DHEAD];  // [64][128] rows 256B
    __shared__ __bf16 Vt_sh[2][DHEAD * KVBLK];  // [128][64] rows 128B (row=d)
    __shared__ __bf16 P_sh [4 * 16 * 72];       // per-wave [16][72]

    const float scale = 0.08838834764831845f; // 1/sqrt(128)

    // ---- Q fragments: row = q0w + r, k = kb*32 + g*8 + e ----
    bf16x8 qfrag[4];
    {
        const float4* qp = reinterpret_cast<const float4*>(
            Qh + (size_t)(q0w + r) * DHEAD + g * 8);
        #pragma unroll
        for (int kb = 0; kb < 4; ++kb) {
            float4 a = qp[kb*8 + 0];
            float4 b = qp[kb*8 + 1];
            a.x*=scale; a.y*=scale; a.z*=scale; a.w*=scale;
            b.x*=scale; b.y*=scale; b.z*=scale; b.w*=scale;
            bf16x8 f;
            f[0]=(__bf16)a.x; f[1]=(__bf16)a.y; f[2]=(__bf16)a.z; f[3]=(__bf16)a.w;
            f[4]=(__bf16)b.x; f[5]=(__bf16)b.y; f[6]=(__bf16)b.z; f[7]=(__bf16)b.w;
            qfrag[kb] = f;
        }
    }

    // staging register tiles (in flight across compute)
    float4 kreg[8], vreg[8];

    const int krow = tid >> 2;        // for K loads: thread -> (row, 32B col)
    const int kc4  = (tid & 3) * 8;   // 8 float4 per thread, strided by 256 thr? no:
    // K: idx = it*256 + tid; row = idx>>5, c4 = idx&31  (same as R1)
    // V: lane covers kv row, wave covers 32-col slab

    auto issue_loads = [&](int kv0) {
        #pragma unroll
        for (int it = 0; it < 8; ++it) {
            const int idx = it * 256 + tid;
            kreg[it] = *reinterpret_cast<const float4*>(
                Kh + (size_t)(kv0 + (idx >> 5)) * DHEAD + (idx & 31) * 4);
        }
        const float* vrow = Vh + (size_t)(kv0 + lane) * DHEAD + w * 32;
        #pragma unroll
        for (int it = 0; it < 8; ++it)
            vreg[it] = *reinterpret_cast<const float4*>(vrow + it * 4);
    };

    auto write_tiles = [&](int buf) {
        char* Kb  = reinterpret_cast<char*>(K_sh[buf]);
        char* Vtb = reinterpret_cast<char*>(Vt_sh[buf]);
        #pragma unroll
        for (int it = 0; it < 8; ++it) {
            const int idx = it * 256 + tid;
            const int row = idx >> 5;
            const int c4  = idx & 31;
            bf16x4 kb4;
            kb4[0]=(__bf16)kreg[it].x; kb4[1]=(__bf16)kreg[it].y;
            kb4[2]=(__bf16)kreg[it].z; kb4[3]=(__bf16)kreg[it].w;
            const int byte = row * 256 + ((c4 * 8) ^ ((row & 7) << 4));
            *reinterpret_cast<bf16x4*>(Kb + byte) = kb4;
        }
        #pragma unroll
        for (int it = 0; it < 8; ++it) {
            #pragma unroll
            for (int j = 0; j < 4; ++j) {
                const int d = w * 32 + it * 4 + j;
                const int byte = d * 128 + ((lane * 2) ^ ((d & 7) << 4));
                *reinterpret_cast<__bf16*>(Vtb + byte) =
                    (__bf16)((&vreg[it].x)[j]);
            }
        }
    };

    const f32x4 vzero = {0.f, 0.f, 0.f, 0.f};
    f32x4 acc_o[8];
    #pragma unroll
    for (int i = 0; i < 8; ++i) acc_o[i] = vzero;
    float m_run[4], l_run[4];
    #pragma unroll
    for (int e = 0; e < 4; ++e) { m_run[e] = -1e30f; l_run[e] = 0.f; }

    // prologue: stage tile 0
    issue_loads(0);
    write_tiles(0);

    int cur = 0;
    for (int kvt = 0; kvt <= qt; ++kvt) {
        const int kv0 = kvt * KVBLK;
        __syncthreads();   // buf[cur] ready (prev iter's / prologue writes)

        const bool more = (kvt < qt);
        if (more) issue_loads(kv0 + KVBLK);   // async: in flight across compute

        char* Kb  = reinterpret_cast<char*>(K_sh[cur]);
        char* Vtb = reinterpret_cast<char*>(Vt_sh[cur]);
        char* Pb  = reinterpret_cast<char*>(P_sh);

        // ---- QK^T: 4 kv-subtiles of 16 ----
        f32x4 acc_s[4];
        #pragma unroll
        for (int t = 0; t < 4; ++t) {
            acc_s[t] = vzero;
            #pragma unroll
            for (int kb = 0; kb < 4; ++kb) {
                const int row  = t * 16 + r;
                const int byte = row * 256 + ((kb*64 + g*16) ^ ((r & 7) << 4));
                bf16x8 kf = *reinterpret_cast<const bf16x8*>(Kb + byte);
                acc_s[t] = __builtin_amdgcn_mfma_f32_16x16x32_bf16(
                    qfrag[kb], kf, acc_s[t], 0, 0, 0);
            }
        }

        // ---- online softmax ----
        const bool diag = (kvt == qt);
        float corr[4];
        #pragma unroll
        for (int e = 0; e < 4; ++e) {
            const int qrow = q0w + g*4 + e;
            float s[4];
            #pragma unroll
            for (int t = 0; t < 4; ++t) {
                s[t] = acc_s[t][e];
                if (diag && (kv0 + t*16 + r > qrow)) s[t] = -1e30f;
            }
            float tm = fmaxf(fmaxf(s[0], s[1]), fmaxf(s[2], s[3]));
            tm = fmaxf(tm, __shfl_xor(tm, 1));
            tm = fmaxf(tm, __shfl_xor(tm, 2));
            tm = fmaxf(tm, __shfl_xor(tm, 4));
            tm = fmaxf(tm, __shfl_xor(tm, 8));
            const float m_new = fmaxf(m_run[e], tm);
            float p[4], rs = 0.f;
            #pragma unroll
            for (int t = 0; t < 4; ++t) { p[t] = __expf(s[t] - m_new); rs += p[t]; }
            rs += __shfl_xor(rs, 1);
            rs += __shfl_xor(rs, 2);
            rs += __shfl_xor(rs, 4);
            rs += __shfl_xor(rs, 8);
            corr[e]  = __expf(m_run[e] - m_new);
            l_run[e] = l_run[e] * corr[e] + rs;
            m_run[e] = m_new;
            #pragma unroll
            for (int t = 0; t < 4; ++t)
                P_sh[(w*16 + g*4 + e) * 72 + t*16 + r] = (__bf16)p[t];
        }

        #pragma unroll
        for (int dt = 0; dt < 8; ++dt)
            #pragma unroll
            for (int e = 0; e < 4; ++e)
                acc_o[dt][e] *= corr[e];

        // wave-local P round-trip: drain DS writes
        asm volatile("s_waitcnt lgkmcnt(0)" ::: "memory");

        // ---- PV ----
        #pragma unroll
        for (int ks = 0; ks < 2; ++ks) {
            const int pbyte = (w*16 + r) * 144 + ks*64 + g*16;
            bf16x8 pa = *reinterpret_cast<const bf16x8*>(Pb + pbyte);
            #pragma unroll
            for (int dt = 0; dt < 8; ++dt) {
                const int row  = dt*16 + r;
                const int byte = row * 128 + ((ks*64 + g*16) ^ ((r & 7) << 4));
                bf16x8 vf = *reinterpret_cast<const bf16x8*>(Vtb + byte);
                acc_o[dt] = __builtin_amdgcn_mfma_f32_16x16x32_bf16(
                    pa, vf, acc_o[dt], 0, 0, 0);
            }
        }

        // write next tile into the other buffer (loads have had ~full
        // compute phase to land; vmcnt wait is implicit at first use)
        if (more) write_tiles(cur ^ 1);
        cur ^= 1;
    }

    // ---- epilogue ----
    #pragma unroll
    for (int e = 0; e < 4; ++e) {
        const float inv = 1.0f / l_run[e];
        float* orow = Oh + (size_t)(q0w + g*4 + e) * DHEAD + r;
        #pragma unroll
        for (int dt = 0; dt < 8; ++dt)
            orow[dt*16] = acc_o[dt][e] * inv;
    }
}

extern "C" void kernel_launch(void* const* d_in, const int* in_sizes, int n_in,
                              void* d_out, int out_size, void* d_ws, size_t ws_size,
                              hipStream_t stream) {
    const float* Q = (const float*)d_in[0];
    const float* K = (const float*)d_in[1];
    const float* V = (const float*)d_in[2];
    float* O = (float*)d_out;
    dim3 grid(32 /* B*H */, NQT);
    attn_fwd<<<grid, 256, 0, stream>>>(Q, K, V, O);
}